// Round 2
// baseline (1252.513 us; speedup 1.0000x reference)
//
#include <hip/hip_runtime.h>

#define N_NODES 50000
#define N_EDGES 800000

typedef unsigned short u16;
typedef unsigned int u32;
typedef __attribute__((ext_vector_type(8))) short short8;
typedef __attribute__((ext_vector_type(4))) float f32x4;
typedef __attribute__((ext_vector_type(2))) float f32x2;

__device__ __forceinline__ u16 f2bf(float f) {
    union { float f; u32 u; } v; v.f = f;
    u32 r = v.u + 0x7FFFu + ((v.u >> 16) & 1u);
    return (u16)(r >> 16);
}

__device__ __forceinline__ float bf2f(u16 h) {
    union { u32 u; float f; } v; v.u = ((u32)h) << 16;
    return v.f;
}

// ---- Wc = Wg @ Wo (f32), bc = bg @ Wo ----
__global__ __launch_bounds__(256) void compute_wc(const float* __restrict__ Wg,
                                                  const float* __restrict__ bg,
                                                  const float* __restrict__ Wo,
                                                  float* __restrict__ Wc,
                                                  float* __restrict__ bc) {
    int b = blockIdx.x;
    if (b < 8) {
        for (int i = 0; i < 8; ++i) {
            int o = b * 2048 + i * 256 + threadIdx.x;
            int k = o >> 7, n = o & 127;
            float s = 0.f;
            for (int j = 0; j < 128; ++j) s += Wg[k * 128 + j] * Wo[j * 128 + n];
            Wc[o] = s;
        }
    } else if (threadIdx.x < 128) {
        int n = threadIdx.x;
        float s = 0.f;
        for (int j = 0; j < 128; ++j) s += bg[j] * Wo[j * 128 + n];
        bc[n] = s;
    }
}

// ---- weight pre-pack: [128x128] f32 -> bf16 B-fragments ----
// dst slot (t*CH + slotBase + c): lane holds B[k=c*32+(lane>>4)*8+j][n=t*16+(lane&15)]
// jobs: 0: W1->PB1 (CH4); 1: W3->PBe slot0 (CH8); 2: W2->PBe slot4 (CH8); 3: Wc->PBc (CH4)
__global__ __launch_bounds__(256) void pack_all(const float* __restrict__ We,
                                                const float* __restrict__ Wc,
                                                u16* __restrict__ PB1,
                                                u16* __restrict__ PBe,
                                                u16* __restrict__ PBc) {
    int bid = blockIdx.x;
    int job = bid >> 3;
    int t = bid & 7;
    const float* src; u16* dst; int slotBase, CH;
    if (job == 0)      { src = We;         dst = PB1; slotBase = 0; CH = 4; }
    else if (job == 1) { src = We + 32768; dst = PBe; slotBase = 0; CH = 8; }
    else if (job == 2) { src = We + 16384; dst = PBe; slotBase = 4; CH = 8; }
    else               { src = Wc;         dst = PBc; slotBase = 0; CH = 4; }
    int c = threadIdx.x >> 6;  // wave = k-chunk
    int lane = threadIdx.x & 63;
    int q = lane >> 4, n = lane & 15;
    const float* s = src + (size_t)(c * 32 + q * 8) * 128 + t * 16 + n;
    u16* dp = dst + (((size_t)(t * CH + slotBase + c) * 64 + lane) * 8);
#pragma unroll
    for (int j = 0; j < 8; ++j) dp[j] = f2bf(s[(size_t)j * 128]);
}

// ---- x -> bf16 copy (for the K=256 fold of the W2 term) ----
__global__ __launch_bounds__(256) void cast_bf16(const float* __restrict__ x,
                                                 u16* __restrict__ X2) {
    size_t i = (size_t)(blockIdx.x * 256 + threadIdx.x) * 8;
    f32x4 v0 = *(const f32x4*)(x + i);
    f32x4 v1 = *(const f32x4*)(x + i + 4);
    short8 o;
#pragma unroll
    for (int j = 0; j < 4; ++j) { o[j] = (short)f2bf(v0[j]); o[4 + j] = (short)f2bf(v1[j]); }
    *(short8*)(X2 + i) = o;
}

// ---- counting sort ----
__global__ __launch_bounds__(256) void hist_kernel(const int* __restrict__ srcIdx,
                                                   const int* __restrict__ dstIdx,
                                                   int* __restrict__ degD,
                                                   int* __restrict__ degS) {
    int e = blockIdx.x * 256 + threadIdx.x;
    if (e >= N_EDGES) return;
    atomicAdd(&degD[dstIdx[e]], 1);
    atomicAdd(&degS[srcIdx[e]], 1);
}

// 2 blocks: block 0 scans degD, block 1 scans degS
__global__ __launch_bounds__(256) void scan_kernel(const int* __restrict__ degD,
                                                   const int* __restrict__ degS,
                                                   int* __restrict__ offD, int* __restrict__ curD,
                                                   int* __restrict__ offS, int* __restrict__ curS) {
    const int* deg = blockIdx.x ? degS : degD;
    int* off = blockIdx.x ? offS : offD;
    int* cur = blockIdx.x ? curS : curD;
    __shared__ int buf[256];
    const int CHUNK = 196;  // 256*196 = 50176 >= 50000
    int tid = threadIdx.x;
    int s0 = tid * CHUNK, s1 = s0 + CHUNK;
    if (s1 > N_NODES) s1 = N_NODES;
    int s = 0;
    for (int i = s0; i < s1; ++i) s += deg[i];
    buf[tid] = s;
    __syncthreads();
    for (int o = 1; o < 256; o <<= 1) {
        int v = (tid >= o) ? buf[tid - o] : 0;
        __syncthreads();
        buf[tid] += v;
        __syncthreads();
    }
    int run = (tid > 0) ? buf[tid - 1] : 0;
    for (int i = s0; i < s1; ++i) {
        off[i] = run;
        cur[i] = run;
        run += deg[i];
    }
    if (tid == 255) off[N_NODES] = buf[255];
}

__global__ __launch_bounds__(256) void scatter_kernel(const int* __restrict__ srcIdx,
                                                      const int* __restrict__ dstIdx,
                                                      int* __restrict__ curD,
                                                      int* __restrict__ curS,
                                                      int2* __restrict__ sdP,
                                                      int* __restrict__ ss_dst) {
    int e = blockIdx.x * 256 + threadIdx.x;
    if (e >= N_EDGES) return;
    int s = srcIdx[e], d = dstIdx[e];
    int p = atomicAdd(&curD[d], 1);
    sdP[p] = make_int2(e, s);
    int p2 = atomicAdd(&curS[s], 1);
    ss_dst[p2] = d;
}

// ---- GEMM: out[M,C] = A[M,128] @ B + bias (+ rowdeg*bias2 if flags&4).
// flags: 1=out bf16, 2=A bf16, 4=row-scaled second bias ----
__global__ __launch_bounds__(256) void gemm_mfma(const void* __restrict__ Ap,
                                                 const u16* __restrict__ PB,
                                                 const float* __restrict__ bias,
                                                 const float* __restrict__ bias2,
                                                 const int* __restrict__ rowdeg,
                                                 void* __restrict__ outp,
                                                 int M, int Ctiles, int flags) {
    int tid = threadIdx.x;
    int wave = tid >> 6;
    int lane = tid & 63;
    int strip = blockIdx.x * 4 + wave;
    int row0 = strip * 16;
    if (row0 >= M) return;
    int q = lane >> 4, n = lane & 15;
    int C = Ctiles * 16;

    short8 a[4];
    if (flags & 2) {
        const u16* ap = (const u16*)Ap + (size_t)(row0 + n) * 128 + q * 8;
#pragma unroll
        for (int c = 0; c < 4; ++c) a[c] = *(const short8*)(ap + c * 32);
    } else {
        const float* ap = (const float*)Ap + (size_t)(row0 + n) * 128 + q * 8;
#pragma unroll
        for (int c = 0; c < 4; ++c) {
            f32x4 f0 = *(const f32x4*)(ap + c * 32);
            f32x4 f1 = *(const f32x4*)(ap + c * 32 + 4);
            short8 t;
#pragma unroll
            for (int j = 0; j < 4; ++j) {
                t[j] = (short)f2bf(f0[j]);
                t[4 + j] = (short)f2bf(f1[j]);
            }
            a[c] = t;
        }
    }

    float rb[4] = {0.f, 0.f, 0.f, 0.f};
    if (flags & 4) {
#pragma unroll
        for (int r = 0; r < 4; ++r) rb[r] = (float)rowdeg[row0 + q * 4 + r];
    }

    for (int t = 0; t < Ctiles; ++t) {
        f32x4 acc = {0.f, 0.f, 0.f, 0.f};
#pragma unroll
        for (int c = 0; c < 4; ++c) {
            short8 b = *(const short8*)(PB + (((size_t)t * 4 + c) * 64 + lane) * 8);
            acc = __builtin_amdgcn_mfma_f32_16x16x32_bf16(a[c], b, acc, 0, 0, 0);
        }
        int col = t * 16 + n;
        float bv = bias ? bias[col] : 0.f;
        float b2 = (flags & 4) ? bias2[col] : 0.f;
#pragma unroll
        for (int r = 0; r < 4; ++r) {
            int row = row0 + q * 4 + r;
            float v = acc[r] + bv + rb[r] * b2;
            if (flags & 1)
                ((u16*)outp)[(size_t)row * C + col] = f2bf(v);
            else
                ((float*)outp)[(size_t)row * C + col] = v;
        }
    }
}

// ---- fused aggregation: 2 waves per dst node (column-split), edges sorted by dst ----
// agg[n] = sum_{e in seg(n)} silu( [EA[e]|X2[src_e]] @ [W3;W2] + T1a[n] )
// K=256 MFMA fold: no LDS, no T1b gather, 2-round latency chain (int2 idx -> gathers).
__global__ __launch_bounds__(256) void agg_fused(const float* __restrict__ EA,
                                                 const u16* __restrict__ X2,
                                                 const u16* __restrict__ PBe,
                                                 const int* __restrict__ offD,
                                                 const int2* __restrict__ sdP,
                                                 const u16* __restrict__ T1a,
                                                 u16* __restrict__ agg) {
    int tid = threadIdx.x;
    int wave = tid >> 6;
    int lane = tid & 63;
    int node = blockIdx.x * 2 + (wave >> 1);
    if (node >= N_NODES) return;
    int cg = wave & 1;  // column group: output tiles cg*4 .. cg*4+3
    int q = lane >> 4, n = lane & 15;
    int segS = offD[node], segE = offD[node + 1];
    const u16* pb = PBe + (size_t)cg * 16384;  // 4 tiles * 8 chunks * 64 * 8

    float g1[4], rowAcc[4];
#pragma unroll
    for (int t = 0; t < 4; ++t) {
        g1[t] = bf2f(T1a[(size_t)node * 128 + (cg * 4 + t) * 16 + n]);
        rowAcc[t] = 0.f;
    }

    for (int base = segS; base < segE; base += 16) {
        int er = base + n;
        if (er > segE - 1) er = segE - 1;  // clamp: duplicate row, masked below
        int2 es = sdP[er];                 // (edge id, src)
        const float* ap = EA + (size_t)es.x * 128 + q * 8;
        const u16* xp = X2 + (size_t)es.y * 128 + q * 8;
        short8 a[8];
#pragma unroll
        for (int c = 0; c < 4; ++c) {
            f32x4 f0 = *(const f32x4*)(ap + c * 32);
            f32x4 f1 = *(const f32x4*)(ap + c * 32 + 4);
            short8 t;
#pragma unroll
            for (int j = 0; j < 4; ++j) {
                t[j] = (short)f2bf(f0[j]);
                t[4 + j] = (short)f2bf(f1[j]);
            }
            a[c] = t;
            a[4 + c] = *(const short8*)(xp + c * 32);
        }
        bool val[4];
#pragma unroll
        for (int r = 0; r < 4; ++r) val[r] = (base + q * 4 + r) < segE;

#pragma unroll
        for (int t = 0; t < 4; ++t) {
            f32x4 acc = {0.f, 0.f, 0.f, 0.f};
#pragma unroll
            for (int c = 0; c < 8; ++c) {
                short8 b = *(const short8*)(pb + (((size_t)t * 8 + c) * 64 + lane) * 8);
                acc = __builtin_amdgcn_mfma_f32_16x16x32_bf16(a[c], b, acc, 0, 0, 0);
            }
#pragma unroll
            for (int r = 0; r < 4; ++r) {
                float v = acc[r] + g1[t];
                float m = v * __builtin_amdgcn_rcpf(1.f + __expf(-v));  // SiLU
                rowAcc[t] += val[r] ? m : 0.f;
            }
        }
    }
    // reduce over the 4 quads (rows) -> full column sums
#pragma unroll
    for (int t = 0; t < 4; ++t) {
        float v = rowAcc[t];
        v += __shfl_xor(v, 16, 64);
        v += __shfl_xor(v, 32, 64);
        if (lane < 16) agg[(size_t)node * 128 + (cg * 4 + t) * 16 + lane] = f2bf(v);
    }
}

// ---- attention sum: one wave per src node, edges sorted by src ----
// G[n] = sum_{e in segS(n)} agg[dst_e]   (bf16 in -> f32 out)
// coalesced index load per 64-edge chunk + shfl broadcast; full wave per row.
__global__ __launch_bounds__(256) void attn_gather(const int* __restrict__ offS,
                                                   const int* __restrict__ ss_dst,
                                                   const u16* __restrict__ hsrc,
                                                   float* __restrict__ attn) {
    int tid = threadIdx.x;
    int wave = tid >> 6;
    int lane = tid & 63;
    int node = blockIdx.x * 4 + wave;
    if (node >= N_NODES) return;
    int e0 = offS[node], e1 = offS[node + 1];
    float a0 = 0.f, a1 = 0.f;  // lane owns cols 2*lane, 2*lane+1
    for (int base = e0; base < e1; base += 64) {
        int m = e1 - base;
        if (m > 64) m = 64;
        int ii = lane < m ? lane : m - 1;
        int myIdx = ss_dst[base + ii];  // coalesced
        int j = 0;
        for (; j + 4 <= m; j += 4) {
            int d0 = __shfl(myIdx, j, 64);
            int d1 = __shfl(myIdx, j + 1, 64);
            int d2 = __shfl(myIdx, j + 2, 64);
            int d3 = __shfl(myIdx, j + 3, 64);
            u32 h0 = *(const u32*)(hsrc + (size_t)d0 * 128 + lane * 2);
            u32 h1 = *(const u32*)(hsrc + (size_t)d1 * 128 + lane * 2);
            u32 h2 = *(const u32*)(hsrc + (size_t)d2 * 128 + lane * 2);
            u32 h3 = *(const u32*)(hsrc + (size_t)d3 * 128 + lane * 2);
            a0 += bf2f((u16)(h0 & 0xFFFFu)) + bf2f((u16)(h1 & 0xFFFFu)) +
                  bf2f((u16)(h2 & 0xFFFFu)) + bf2f((u16)(h3 & 0xFFFFu));
            a1 += bf2f((u16)(h0 >> 16)) + bf2f((u16)(h1 >> 16)) +
                  bf2f((u16)(h2 >> 16)) + bf2f((u16)(h3 >> 16));
        }
        for (; j < m; ++j) {
            int d = __shfl(myIdx, j, 64);
            u32 h = *(const u32*)(hsrc + (size_t)d * 128 + lane * 2);
            a0 += bf2f((u16)(h & 0xFFFFu));
            a1 += bf2f((u16)(h >> 16));
        }
    }
    f32x2 o;
    o[0] = a0;
    o[1] = a1;
    *(f32x2*)(attn + (size_t)node * 128 + lane * 2) = o;
}

extern "C" void kernel_launch(void* const* d_in, const int* in_sizes, int n_in,
                              void* d_out, int out_size, void* d_ws, size_t ws_size,
                              hipStream_t stream) {
    const float* x  = (const float*)d_in[0];
    const int* ei   = (const int*)d_in[1];
    const float* ea = (const float*)d_in[2];
    const float* We = (const float*)d_in[3];
    const float* be = (const float*)d_in[4];
    const float* Wg = (const float*)d_in[5];
    const float* bg = (const float*)d_in[6];
    // d_in[7]=Wa, d_in[8]=ba: dead — softmax over a size-1 axis is identically 1
    const float* Wo = (const float*)d_in[9];
    const float* bo = (const float*)d_in[10];
    float* out = (float*)d_out;

    const int* srcIdx = ei;            // edge_index[0]
    const int* dstIdx = ei + N_EDGES;  // edge_index[1]

    char* ws = (char*)d_ws;
    u16*   PB1    = (u16*)(ws + 0);          // 32 KiB  (W1)
    u16*   PBe    = (u16*)(ws + 32768);      // 64 KiB  ([W3;W2] K=256)
    u16*   PBc    = (u16*)(ws + 98304);      // 32 KiB  (Wg@Wo)
    float* Wc     = (float*)(ws + 131072);   // 64 KiB f32
    float* bc     = (float*)(ws + 196608);   // 512 B (bg@Wo)
    u16*   T1a    = (u16*)(ws + 262144);     // [N,128] bf16, 12.8 MB
    u16*   X2     = (u16*)(ws + 13062144);   // [N,128] bf16, 12.8 MB
    float* attn   = (float*)(ws + 262144);   // alias: T1a+X2 dead after agg_fused (25.6 MB)
    u16*   agg    = (u16*)(ws + 25862144);   // [N,128] bf16, 12.8 MB
    int*   degD   = (int*)(ws + 38662144);   // 200 KB
    int*   degS   = (int*)(ws + 38862144);   // 200 KB
    int*   offD   = (int*)(ws + 39062144);   // 200 KB + pad
    int*   offS   = (int*)(ws + 39262160);
    int*   curD   = (int*)(ws + 39462176);
    int*   curS   = (int*)(ws + 39662176);
    int2*  sdP    = (int2*)(ws + 39862176);  // 6.4 MB: (edge id, src), sorted by dst
    int*   ss_dst = (int*)(ws + 46262176);   // 3.2 MB: dst, sorted by src

    hipMemsetAsync(degD, 0, 400000, stream);  // degD + degS (contiguous)

    compute_wc<<<9, 256, 0, stream>>>(Wg, bg, Wo, Wc, bc);
    pack_all<<<32, 256, 0, stream>>>(We, Wc, PB1, PBe, PBc);

    // counting sorts: by dst (agg) and by src (attn)
    hist_kernel<<<3125, 256, 0, stream>>>(srcIdx, dstIdx, degD, degS);
    scan_kernel<<<2, 256, 0, stream>>>(degD, degS, offD, curD, offS, curS);
    scatter_kernel<<<3125, 256, 0, stream>>>(srcIdx, dstIdx, curD, curS, sdP, ss_dst);

    cast_bf16<<<3125, 256, 0, stream>>>(x, X2);

    // T1a = x@W1 + be  (bf16)
    gemm_mfma<<<782, 256, 0, stream>>>(x, PB1, be, nullptr, nullptr, T1a, N_NODES, 8, 1);

    // agg[n] = sum over dst-segment of silu(...)  — no atomics, no LDS
    agg_fused<<<25000, 256, 0, stream>>>(ea, X2, PBe, offD, sdP, T1a, agg);

    // G[n] = sum over src-segment of agg[dst]  (writes over dead T1a/X2)
    attn_gather<<<12500, 256, 0, stream>>>(offS, ss_dst, agg, attn);

    // out = G@(Wg@Wo) + degS*(bg@Wo) + bo  (f32)
    gemm_mfma<<<782, 256, 0, stream>>>(attn, PBc, bo, bc, degS, out, N_NODES, 8, 4);

    (void)in_sizes; (void)n_in; (void)out_size; (void)ws_size;
}

// Round 3
// 1230.006 us; speedup vs baseline: 1.0183x; 1.0183x over previous
//
#include <hip/hip_runtime.h>

#define N_NODES 50000
#define N_EDGES 800000
#define N_TILES 50000  // N_EDGES / 16, exact

typedef unsigned short u16;
typedef unsigned int u32;
typedef __attribute__((ext_vector_type(8))) short short8;
typedef __attribute__((ext_vector_type(4))) float f32x4;
typedef __attribute__((ext_vector_type(2))) float f32x2;

__device__ __forceinline__ u16 f2bf(float f) {
    union { float f; u32 u; } v; v.f = f;
    u32 r = v.u + 0x7FFFu + ((v.u >> 16) & 1u);
    return (u16)(r >> 16);
}

__device__ __forceinline__ float bf2f(u16 h) {
    union { u32 u; float f; } v; v.u = ((u32)h) << 16;
    return v.f;
}

// ---- prep: x->bf16 cast, zero agg, zero deg, pack [W3;W2;W1] (K=384), pack Wg@Wo, bc ----
// block ranges: [0,3125) cast; [3125,4725) zero agg; [4725,4823) zero deg;
//               [4823,4847) pack PBe; [4847,4855) Wc->PBc packed; [4855] bc
__global__ __launch_bounds__(256) void prep_kernel(const float* __restrict__ x,
                                                   const float* __restrict__ We,
                                                   const float* __restrict__ Wg,
                                                   const float* __restrict__ bg,
                                                   const float* __restrict__ Wo,
                                                   u16* __restrict__ Xbf,
                                                   u16* __restrict__ PBe,
                                                   u16* __restrict__ PBc,
                                                   float* __restrict__ bc,
                                                   float* __restrict__ aggF,
                                                   int* __restrict__ degZ) {
    int b = blockIdx.x, tid = threadIdx.x;
    if (b < 3125) {  // cast x -> bf16 (6.4M elems, exact)
        size_t i = ((size_t)b * 256 + tid) * 8;
        f32x4 v0 = *(const f32x4*)(x + i);
        f32x4 v1 = *(const f32x4*)(x + i + 4);
        short8 o;
#pragma unroll
        for (int j = 0; j < 4; ++j) { o[j] = (short)f2bf(v0[j]); o[4 + j] = (short)f2bf(v1[j]); }
        *(short8*)(Xbf + i) = o;
    } else if (b < 4725) {  // zero agg (6.4M f32)
        int bb = b - 3125;
#pragma unroll
        for (int k = 0; k < 4; ++k) {
            int idx4 = bb * 1024 + k * 256 + tid;
            if (idx4 < 1600000) ((f32x4*)aggF)[idx4] = (f32x4){0.f, 0.f, 0.f, 0.f};
        }
    } else if (b < 4823) {  // zero degD+degS (100000 ints contiguous)
        int idx4 = (b - 4725) * 256 + tid;
        if (idx4 < 25000) ((int4*)degZ)[idx4] = make_int4(0, 0, 0, 0);
    } else if (b < 4847) {  // pack PBe: jb0=W3(slots0-3), jb1=W2(4-7), jb2=W1(8-11)
        int bb = b - 4823;
        int jb = bb >> 3, t = bb & 7;
        const float* src = (jb == 0) ? We + 32768 : (jb == 1) ? We + 16384 : We;
        int c = tid >> 6, lane = tid & 63, q = lane >> 4, n = lane & 15;
        int slot = jb * 4 + c;
        const float* s = src + (size_t)(c * 32 + q * 8) * 128 + t * 16 + n;
        u16* dp = PBe + (((size_t)(t * 12 + slot) * 64 + lane) * 8);
#pragma unroll
        for (int j = 0; j < 8; ++j) dp[j] = f2bf(s[(size_t)j * 128]);
    } else if (b < 4855) {  // Wc = Wg@Wo, written directly in packed B-fragment form
        int w = b - 4847;
        for (int i = 0; i < 8; ++i) {
            int o = w * 2048 + i * 256 + tid;
            int k = o >> 7, n = o & 127;
            float s = 0.f;
            for (int j = 0; j < 128; ++j) s += Wg[k * 128 + j] * Wo[j * 128 + n];
            int t = n >> 4, c = k >> 5, q = (k >> 3) & 3, j8 = k & 7;
            int ln = (q << 4) | (n & 15);
            PBc[(((size_t)(t * 4 + c) * 64 + ln) * 8) + j8] = f2bf(s);
        }
    } else {  // bc = bg@Wo
        if (tid < 128) {
            float s = 0.f;
            for (int j = 0; j < 128; ++j) s += bg[j] * Wo[j * 128 + tid];
            bc[tid] = s;
        }
    }
}

// ---- counting sort ----
__global__ __launch_bounds__(256) void hist_kernel(const int* __restrict__ srcIdx,
                                                   const int* __restrict__ dstIdx,
                                                   int* __restrict__ degD,
                                                   int* __restrict__ degS) {
    int e = blockIdx.x * 256 + threadIdx.x;
    if (e >= N_EDGES) return;
    atomicAdd(&degD[dstIdx[e]], 1);
    atomicAdd(&degS[srcIdx[e]], 1);
}

// 2 blocks: block 0 scans degD, block 1 scans degS
__global__ __launch_bounds__(256) void scan_kernel(const int* __restrict__ degD,
                                                   const int* __restrict__ degS,
                                                   int* __restrict__ offD, int* __restrict__ curD,
                                                   int* __restrict__ offS, int* __restrict__ curS) {
    const int* deg = blockIdx.x ? degS : degD;
    int* off = blockIdx.x ? offS : offD;
    int* cur = blockIdx.x ? curS : curD;
    __shared__ int buf[256];
    const int CHUNK = 196;  // 256*196 = 50176 >= 50000
    int tid = threadIdx.x;
    int s0 = tid * CHUNK, s1 = s0 + CHUNK;
    if (s1 > N_NODES) s1 = N_NODES;
    int s = 0;
    for (int i = s0; i < s1; ++i) s += deg[i];
    buf[tid] = s;
    __syncthreads();
    for (int o = 1; o < 256; o <<= 1) {
        int v = (tid >= o) ? buf[tid - o] : 0;
        __syncthreads();
        buf[tid] += v;
        __syncthreads();
    }
    int run = (tid > 0) ? buf[tid - 1] : 0;
    for (int i = s0; i < s1; ++i) {
        off[i] = run;
        cur[i] = run;
        run += deg[i];
    }
    if (tid == 255) off[N_NODES] = buf[255];
}

__global__ __launch_bounds__(256) void scatter_kernel(const int* __restrict__ srcIdx,
                                                      const int* __restrict__ dstIdx,
                                                      int* __restrict__ curD,
                                                      int* __restrict__ curS,
                                                      int4* __restrict__ sdP,
                                                      int* __restrict__ ss_dst) {
    int e = blockIdx.x * 256 + threadIdx.x;
    if (e >= N_EDGES) return;
    int s = srcIdx[e], d = dstIdx[e];
    int p = atomicAdd(&curD[d], 1);
    sdP[p] = make_int4(e, s, d, 0);
    int p2 = atomicAdd(&curS[s], 1);
    ss_dst[p2] = d;
}

// ---- GEMM: out[M,C] = A[M,128] @ B + bias + rowdeg*bias2 (f32 in/out) ----
__global__ __launch_bounds__(256) void gemm_mfma(const float* __restrict__ Ap,
                                                 const u16* __restrict__ PB,
                                                 const float* __restrict__ bias,
                                                 const float* __restrict__ bias2,
                                                 const int* __restrict__ rowdeg,
                                                 float* __restrict__ outp,
                                                 int M, int Ctiles) {
    int tid = threadIdx.x;
    int wave = tid >> 6;
    int lane = tid & 63;
    int strip = blockIdx.x * 4 + wave;
    int row0 = strip * 16;
    if (row0 >= M) return;
    int q = lane >> 4, n = lane & 15;
    int C = Ctiles * 16;

    short8 a[4];
    const float* ap = Ap + (size_t)(row0 + n) * 128 + q * 8;
#pragma unroll
    for (int c = 0; c < 4; ++c) {
        f32x4 f0 = *(const f32x4*)(ap + c * 32);
        f32x4 f1 = *(const f32x4*)(ap + c * 32 + 4);
        short8 t;
#pragma unroll
        for (int j = 0; j < 4; ++j) {
            t[j] = (short)f2bf(f0[j]);
            t[4 + j] = (short)f2bf(f1[j]);
        }
        a[c] = t;
    }

    float rb[4];
#pragma unroll
    for (int r = 0; r < 4; ++r) rb[r] = (float)rowdeg[row0 + q * 4 + r];

    for (int t = 0; t < Ctiles; ++t) {
        f32x4 acc = {0.f, 0.f, 0.f, 0.f};
#pragma unroll
        for (int c = 0; c < 4; ++c) {
            short8 b = *(const short8*)(PB + (((size_t)t * 4 + c) * 64 + lane) * 8);
            acc = __builtin_amdgcn_mfma_f32_16x16x32_bf16(a[c], b, acc, 0, 0, 0);
        }
        int col = t * 16 + n;
        float bv = bias[col];
        float b2 = bias2[col];
#pragma unroll
        for (int r = 0; r < 4; ++r) {
            int row = row0 + q * 4 + r;
            outp[(size_t)row * C + col] = acc[r] + bv + rb[r] * b2;
        }
    }
}

// ---- fused aggregation: one wave per 16-edge tile, edges sorted by dst ----
// m_row = silu([EA[e] | Xbf[src] | Xbf[dst]] @ [W3;W2;W1] + be)  (K=384 fold)
// agg[dst] += m_row via in-register run-collapse (dst-sorted) + f32 atomics.
__global__ __launch_bounds__(256) void agg_fused(const float* __restrict__ EA,
                                                 const u16* __restrict__ Xbf,
                                                 const u16* __restrict__ PBe,
                                                 const float* __restrict__ be,
                                                 const int4* __restrict__ sdP,
                                                 float* __restrict__ aggF) {
    int tid = threadIdx.x;
    int wave = tid >> 6;
    int lane = tid & 63;
    int tile = blockIdx.x * 4 + wave;  // grid covers exactly N_TILES
    int q = lane >> 4, n = lane & 15;

    int4 es = sdP[tile * 16 + n];  // (edge, src, dst, 0) — coalesced, 4-way broadcast
    const float* ap = EA + (size_t)es.x * 128 + q * 8;
    const u16* xs = Xbf + (size_t)es.y * 128 + q * 8;
    const u16* xd = Xbf + (size_t)es.z * 128 + q * 8;

    short8 a[12];
#pragma unroll
    for (int c = 0; c < 4; ++c) {
        f32x4 f0 = *(const f32x4*)(ap + c * 32);
        f32x4 f1 = *(const f32x4*)(ap + c * 32 + 4);
        short8 t;
#pragma unroll
        for (int j = 0; j < 4; ++j) {
            t[j] = (short)f2bf(f0[j]);
            t[4 + j] = (short)f2bf(f1[j]);
        }
        a[c] = t;          // EA  @ W3
        a[4 + c] = *(const short8*)(xs + c * 32);  // x[src] @ W2
        a[8 + c] = *(const short8*)(xd + c * 32);  // x[dst] @ W1
    }

    // dst of this lane's 4 C-rows (row = q*4+r); lanes 0..15 hold rows 0..15
    int d0 = __shfl(es.z, q * 4 + 0, 64);
    int d1 = __shfl(es.z, q * 4 + 1, 64);
    int d2 = __shfl(es.z, q * 4 + 2, 64);
    int d3 = __shfl(es.z, q * 4 + 3, 64);
    bool c1 = (d1 == d0), c2 = (d2 == d1), c3 = (d3 == d2);

    float bb[8];
#pragma unroll
    for (int t = 0; t < 8; ++t) bb[t] = be[t * 16 + n];

#pragma unroll
    for (int t = 0; t < 8; ++t) {
        f32x4 acc = {0.f, 0.f, 0.f, 0.f};
#pragma unroll
        for (int c = 0; c < 12; ++c) {
            short8 b = *(const short8*)(PBe + (((size_t)t * 12 + c) * 64 + lane) * 8);
            acc = __builtin_amdgcn_mfma_f32_16x16x32_bf16(a[c], b, acc, 0, 0, 0);
        }
        float v0 = acc[0] + bb[t], v1 = acc[1] + bb[t], v2 = acc[2] + bb[t], v3 = acc[3] + bb[t];
        v0 *= __builtin_amdgcn_rcpf(1.f + __expf(-v0));  // SiLU
        v1 *= __builtin_amdgcn_rcpf(1.f + __expf(-v1));
        v2 *= __builtin_amdgcn_rcpf(1.f + __expf(-v2));
        v3 *= __builtin_amdgcn_rcpf(1.f + __expf(-v3));
        // segmented prefix with resets; flush at run ends
        float s0 = v0;
        float s1 = v1 + (c1 ? s0 : 0.f);
        float s2 = v2 + (c2 ? s1 : 0.f);
        float s3 = v3 + (c3 ? s2 : 0.f);
        float* basep = aggF + t * 16 + n;
        if (!c1) atomicAdd(basep + (size_t)d0 * 128, s0);
        if (!c2) atomicAdd(basep + (size_t)d1 * 128, s1);
        if (!c3) atomicAdd(basep + (size_t)d2 * 128, s2);
        atomicAdd(basep + (size_t)d3 * 128, s3);
    }
}

// ---- attention sum: one wave per src node, edges sorted by src ----
// attnB[n] = sum_{e in segS(n)} agg[dst_e]  (f32); 16 gathers per round, all issued at once.
__global__ __launch_bounds__(256) void attn_gather(const int* __restrict__ offS,
                                                   const int* __restrict__ ss_dst,
                                                   const float* __restrict__ aggF,
                                                   float* __restrict__ attnB) {
    int tid = threadIdx.x;
    int wave = tid >> 6;
    int lane = tid & 63;
    int node = blockIdx.x * 4 + wave;
    if (node >= N_NODES) return;
    int e0 = offS[node], e1 = offS[node + 1];
    float a0 = 0.f, a1 = 0.f;  // lane owns cols 2*lane, 2*lane+1
    for (int base = e0; base < e1; base += 16) {
        int m = e1 - base;
        if (m > 16) m = 16;
        int ii = base + (lane & 15);
        if (ii > e1 - 1) ii = e1 - 1;
        int idxv = ss_dst[ii];  // coalesced, 4-way broadcast
#pragma unroll
        for (int i = 0; i < 16; ++i) {
            bool val = i < m;  // wave-uniform
            int d = __shfl(idxv, val ? i : 0, 64);
            f32x2 h = *(const f32x2*)(aggF + (size_t)d * 128 + lane * 2);
            a0 += val ? h[0] : 0.f;
            a1 += val ? h[1] : 0.f;
        }
    }
    f32x2 o;
    o[0] = a0;
    o[1] = a1;
    *(f32x2*)(attnB + (size_t)node * 128 + lane * 2) = o;
}

extern "C" void kernel_launch(void* const* d_in, const int* in_sizes, int n_in,
                              void* d_out, int out_size, void* d_ws, size_t ws_size,
                              hipStream_t stream) {
    const float* x  = (const float*)d_in[0];
    const int* ei   = (const int*)d_in[1];
    const float* ea = (const float*)d_in[2];
    const float* We = (const float*)d_in[3];
    const float* be = (const float*)d_in[4];
    const float* Wg = (const float*)d_in[5];
    const float* bg = (const float*)d_in[6];
    // d_in[7]=Wa, d_in[8]=ba: dead — softmax over a size-1 axis is identically 1
    const float* Wo = (const float*)d_in[9];
    const float* bo = (const float*)d_in[10];
    float* out = (float*)d_out;

    const int* srcIdx = ei;            // edge_index[0]
    const int* dstIdx = ei + N_EDGES;  // edge_index[1]

    char* ws = (char*)d_ws;
    u16*   PBe    = (u16*)(ws + 0);          // 96 KiB  [W3;W2;W1] K=384
    u16*   PBc    = (u16*)(ws + 98304);      // 32 KiB  (Wg@Wo packed)
    float* bc     = (float*)(ws + 131072);   // 512 B   (bg@Wo)
    u16*   Xbf    = (u16*)(ws + 262144);     // [N,128] bf16, 12.8 MB -> ends 13,062,144
    int4*  sdP    = (int4*)(ws + 13062144);  // 12.8 MB (e,src,dst,0) dst-sorted -> ends 25,862,144
    float* attnB  = (float*)(ws + 262144);   // alias over Xbf+sdP (dead after agg), 25.6 MB
    int*   ss_dst = (int*)(ws + 25862144);   // 3.2 MB dst, src-sorted -> ends 29,062,144
    float* aggF   = (float*)(ws + 29062144); // [N,128] f32, 25.6 MB -> ends 54,662,144
    int*   degD   = (int*)(ws + 54662144);   // 200 KB (degS contiguous after)
    int*   degS   = (int*)(ws + 54862144);   // 200 KB
    int*   offD   = (int*)(ws + 55062144);   // 200,016 B
    int*   offS   = (int*)(ws + 55262160);   // 200,016 B
    int*   curD   = (int*)(ws + 55462176);   // 200 KB
    int*   curS   = (int*)(ws + 55662176);   // 200 KB -> ends 55,862,176

    // 1: all preprocessing + zeroing in one kernel
    prep_kernel<<<4856, 256, 0, stream>>>(x, We, Wg, bg, Wo, Xbf, PBe, PBc, bc, aggF, degD);

    // 2-4: counting sorts (by dst for agg, by src for attn)
    hist_kernel<<<3125, 256, 0, stream>>>(srcIdx, dstIdx, degD, degS);
    scan_kernel<<<2, 256, 0, stream>>>(degD, degS, offD, curD, offS, curS);
    scatter_kernel<<<3125, 256, 0, stream>>>(srcIdx, dstIdx, curD, curS, sdP, ss_dst);

    // 5: edge-tile message GEMM (K=384) + run-collapsed atomic aggregation
    agg_fused<<<12500, 256, 0, stream>>>(ea, Xbf, PBe, be, sdP, aggF);

    // 6: attnB[n] = sum over src-segment of agg[dst]  (writes over dead Xbf/sdP)
    attn_gather<<<12500, 256, 0, stream>>>(offS, ss_dst, aggF, attnB);

    // 7: out = attnB@(Wg@Wo) + degS*(bg@Wo) + bo
    gemm_mfma<<<782, 256, 0, stream>>>(attnB, PBc, bo, bc, degS, out, N_NODES, 8);

    (void)in_sizes; (void)n_in; (void)out_size; (void)ws_size;
}

// Round 4
// 1165.211 us; speedup vs baseline: 1.0749x; 1.0556x over previous
//
#include <hip/hip_runtime.h>

#define N_NODES 50000
#define N_EDGES 800000
#define N_TILES 50000  // N_EDGES / 16, exact

typedef unsigned short u16;
typedef unsigned int u32;
typedef __attribute__((ext_vector_type(8))) short short8;
typedef __attribute__((ext_vector_type(4))) float f32x4;
typedef __attribute__((ext_vector_type(2))) float f32x2;

__device__ __forceinline__ u16 f2bf(float f) {
    union { float f; u32 u; } v; v.f = f;
    u32 r = v.u + 0x7FFFu + ((v.u >> 16) & 1u);
    return (u16)(r >> 16);
}

__device__ __forceinline__ float bf2f(u16 h) {
    union { u32 u; float f; } v; v.u = ((u32)h) << 16;
    return v.f;
}

// ---- prep: x->bf16 cast, zero agg, zero deg, pack [W3;W2;W1] (K=384), pack Wg@Wo, bc ----
// block ranges: [0,3125) cast; [3125,4725) zero agg; [4725,4823) zero deg;
//               [4823,4847) pack PBe; [4847,4855) Wc->PBc packed; [4855] bc
__global__ __launch_bounds__(256) void prep_kernel(const float* __restrict__ x,
                                                   const float* __restrict__ We,
                                                   const float* __restrict__ Wg,
                                                   const float* __restrict__ bg,
                                                   const float* __restrict__ Wo,
                                                   u16* __restrict__ Xbf,
                                                   u16* __restrict__ PBe,
                                                   u16* __restrict__ PBc,
                                                   float* __restrict__ bc,
                                                   float* __restrict__ aggF,
                                                   int* __restrict__ degZ) {
    int b = blockIdx.x, tid = threadIdx.x;
    if (b < 3125) {  // cast x -> bf16 (6.4M elems, exact)
        size_t i = ((size_t)b * 256 + tid) * 8;
        f32x4 v0 = *(const f32x4*)(x + i);
        f32x4 v1 = *(const f32x4*)(x + i + 4);
        short8 o;
#pragma unroll
        for (int j = 0; j < 4; ++j) { o[j] = (short)f2bf(v0[j]); o[4 + j] = (short)f2bf(v1[j]); }
        *(short8*)(Xbf + i) = o;
    } else if (b < 4725) {  // zero agg (6.4M f32)
        int bb = b - 3125;
#pragma unroll
        for (int k = 0; k < 4; ++k) {
            int idx4 = bb * 1024 + k * 256 + tid;
            if (idx4 < 1600000) ((f32x4*)aggF)[idx4] = (f32x4){0.f, 0.f, 0.f, 0.f};
        }
    } else if (b < 4823) {  // zero degD+degS (100000 ints contiguous)
        int idx4 = (b - 4725) * 256 + tid;
        if (idx4 < 25000) ((int4*)degZ)[idx4] = make_int4(0, 0, 0, 0);
    } else if (b < 4847) {  // pack PBe: jb0=W3(slots0-3), jb1=W2(4-7), jb2=W1(8-11)
        int bb = b - 4823;
        int jb = bb >> 3, t = bb & 7;
        const float* src = (jb == 0) ? We + 32768 : (jb == 1) ? We + 16384 : We;
        int c = tid >> 6, lane = tid & 63, q = lane >> 4, n = lane & 15;
        int slot = jb * 4 + c;
        const float* s = src + (size_t)(c * 32 + q * 8) * 128 + t * 16 + n;
        u16* dp = PBe + (((size_t)(t * 12 + slot) * 64 + lane) * 8);
#pragma unroll
        for (int j = 0; j < 8; ++j) dp[j] = f2bf(s[(size_t)j * 128]);
    } else if (b < 4855) {  // Wc = Wg@Wo, written directly in packed B-fragment form
        int w = b - 4847;
        for (int i = 0; i < 8; ++i) {
            int o = w * 2048 + i * 256 + tid;
            int k = o >> 7, n = o & 127;
            float s = 0.f;
            for (int j = 0; j < 128; ++j) s += Wg[k * 128 + j] * Wo[j * 128 + n];
            int t = n >> 4, c = k >> 5, q = (k >> 3) & 3, j8 = k & 7;
            int ln = (q << 4) | (n & 15);
            PBc[(((size_t)(t * 4 + c) * 64 + ln) * 8) + j8] = f2bf(s);
        }
    } else {  // bc = bg@Wo
        if (tid < 128) {
            float s = 0.f;
            for (int j = 0; j < 128; ++j) s += bg[j] * Wo[j * 128 + tid];
            bc[tid] = s;
        }
    }
}

// ---- counting sort ----
__global__ __launch_bounds__(256) void hist_kernel(const int* __restrict__ srcIdx,
                                                   const int* __restrict__ dstIdx,
                                                   int* __restrict__ degD,
                                                   int* __restrict__ degS) {
    int e = blockIdx.x * 256 + threadIdx.x;
    if (e >= N_EDGES) return;
    atomicAdd(&degD[dstIdx[e]], 1);
    atomicAdd(&degS[srcIdx[e]], 1);
}

// 2 blocks: block 0 scans degD, block 1 scans degS (int4 vectorized)
__global__ __launch_bounds__(256) void scan_kernel(const int* __restrict__ degD,
                                                   const int* __restrict__ degS,
                                                   int* __restrict__ offD, int* __restrict__ curD,
                                                   int* __restrict__ offS, int* __restrict__ curS) {
    const int* deg = blockIdx.x ? degS : degD;
    int* off = blockIdx.x ? offS : offD;
    int* cur = blockIdx.x ? curS : curD;
    __shared__ int buf[256];
    const int CHUNK = 196;  // 256*196 = 50176 >= 50000; CHUNK%4==0
    int tid = threadIdx.x;
    int s0 = tid * CHUNK, s1 = s0 + CHUNK;
    if (s1 > N_NODES) s1 = N_NODES;
    int i40 = s0 >> 2, i41 = s1 >> 2;
    const int4* deg4 = (const int4*)deg;
    int s = 0;
    for (int i = i40; i < i41; ++i) {
        int4 v = deg4[i];
        s += v.x + v.y + v.z + v.w;
    }
    buf[tid] = s;
    __syncthreads();
    for (int o = 1; o < 256; o <<= 1) {
        int v = (tid >= o) ? buf[tid - o] : 0;
        __syncthreads();
        buf[tid] += v;
        __syncthreads();
    }
    int run = (tid > 0) ? buf[tid - 1] : 0;
    for (int i = i40; i < i41; ++i) {
        int4 v = deg4[i];
        int4 o;
        o.x = run;
        o.y = o.x + v.x;
        o.z = o.y + v.y;
        o.w = o.z + v.z;
        ((int4*)off)[i] = o;
        ((int4*)cur)[i] = o;
        run = o.w + v.w;
    }
    if (tid == 255) off[N_NODES] = buf[255];
}

__global__ __launch_bounds__(256) void scatter_kernel(const int* __restrict__ srcIdx,
                                                      const int* __restrict__ dstIdx,
                                                      int* __restrict__ curD,
                                                      int* __restrict__ curS,
                                                      int4* __restrict__ sdP,
                                                      int* __restrict__ ss_dst) {
    int e = blockIdx.x * 256 + threadIdx.x;
    if (e >= N_EDGES) return;
    int s = srcIdx[e], d = dstIdx[e];
    int p = atomicAdd(&curD[d], 1);
    sdP[p] = make_int4(e, s, d, 0);
    int p2 = atomicAdd(&curS[s], 1);
    ss_dst[p2] = d;
}

// ---- GEMM: out[M,128] = A[M,128](f32, cast bf16) @ PB (no bias) ----
__global__ __launch_bounds__(256) void gemm_mfma(const float* __restrict__ Ap,
                                                 const u16* __restrict__ PB,
                                                 float* __restrict__ outp,
                                                 int M) {
    int tid = threadIdx.x;
    int wave = tid >> 6;
    int lane = tid & 63;
    int strip = blockIdx.x * 4 + wave;
    int row0 = strip * 16;
    if (row0 >= M) return;
    int q = lane >> 4, n = lane & 15;

    short8 a[4];
    const float* ap = Ap + (size_t)(row0 + n) * 128 + q * 8;
#pragma unroll
    for (int c = 0; c < 4; ++c) {
        f32x4 f0 = *(const f32x4*)(ap + c * 32);
        f32x4 f1 = *(const f32x4*)(ap + c * 32 + 4);
        short8 t;
#pragma unroll
        for (int j = 0; j < 4; ++j) {
            t[j] = (short)f2bf(f0[j]);
            t[4 + j] = (short)f2bf(f1[j]);
        }
        a[c] = t;
    }

    for (int t = 0; t < 8; ++t) {
        f32x4 acc = {0.f, 0.f, 0.f, 0.f};
#pragma unroll
        for (int c = 0; c < 4; ++c) {
            short8 b = *(const short8*)(PB + (((size_t)t * 4 + c) * 64 + lane) * 8);
            acc = __builtin_amdgcn_mfma_f32_16x16x32_bf16(a[c], b, acc, 0, 0, 0);
        }
        int col = t * 16 + n;
#pragma unroll
        for (int r = 0; r < 4; ++r) {
            int row = row0 + q * 4 + r;
            outp[(size_t)row * 128 + col] = acc[r];
        }
    }
}

// ---- fused aggregation: block = 4 waves x same 8 edge-tiles; wave owns 2 column-tiles.
// m_row = silu([EA[e] | Xbf[src] | Xbf[dst]] @ [W3;W2;W1] + be)  (K=384 fold)
// B slice (24 short8) preloaded into registers -> zero B traffic in the loop.
// Full 16-row segmented run-collapse (cross-quad carry via 3 shfl steps) -> atomics
// only at true run ends. XCD-chunked block swizzle keeps node ranges XCD-local.
__global__ __launch_bounds__(256) void agg_fused(const float* __restrict__ EA,
                                                 const u16* __restrict__ Xbf,
                                                 const u16* __restrict__ PBe,
                                                 const float* __restrict__ be,
                                                 const int4* __restrict__ sdP,
                                                 float* __restrict__ aggF) {
    int tid = threadIdx.x;
    int wave = tid >> 6;
    int lane = tid & 63;
    int q = lane >> 4, n = lane & 15;

    // bijective XCD-chunk swizzle: grid 6250 = 8*781 + 2 (xcd 0,1 get 782)
    int bid = blockIdx.x;
    int xcd = bid & 7, pos = bid >> 3;
    int blk = (xcd < 2 ? xcd * 782 : 1564 + (xcd - 2) * 781) + pos;
    int tileBase = blk * 8;

    int t0 = wave * 2;  // this wave's 2 column-tiles
    short8 B[24];
#pragma unroll
    for (int tt = 0; tt < 2; ++tt)
#pragma unroll
        for (int c = 0; c < 12; ++c)
            B[tt * 12 + c] = *(const short8*)(PBe + (((size_t)(t0 + tt) * 12 + c) * 64 + lane) * 8);
    float bb[2] = {be[t0 * 16 + n], be[t0 * 16 + 16 + n]};

    for (int s = 0; s < 8; ++s) {
        int tile = tileBase + s;
        int4 es = sdP[tile * 16 + n];  // (edge, src, dst, 0) — coalesced, 4-way bcast
        const float* ap = EA + (size_t)es.x * 128 + q * 8;
        const u16* xs = Xbf + (size_t)es.y * 128 + q * 8;
        const u16* xd = Xbf + (size_t)es.z * 128 + q * 8;

        short8 a[12];
#pragma unroll
        for (int c = 0; c < 4; ++c) {
            f32x4 f0 = *(const f32x4*)(ap + c * 32);
            f32x4 f1 = *(const f32x4*)(ap + c * 32 + 4);
            short8 t;
#pragma unroll
            for (int j = 0; j < 4; ++j) {
                t[j] = (short)f2bf(f0[j]);
                t[4 + j] = (short)f2bf(f1[j]);
            }
            a[c] = t;                                  // EA     @ W3
            a[4 + c] = *(const short8*)(xs + c * 32);  // x[src] @ W2
            a[8 + c] = *(const short8*)(xd + c * 32);  // x[dst] @ W1
        }

        // dst of my quad's 4 rows + neighbors for cross-quad runs
        int d0 = __shfl(es.z, q * 4 + 0, 64);
        int d1 = __shfl(es.z, q * 4 + 1, 64);
        int d2 = __shfl(es.z, q * 4 + 2, 64);
        int d3 = __shfl(es.z, q * 4 + 3, 64);
        bool c1 = (d1 == d0), c2 = (d2 == d1), c3 = (d3 == d2);
        bool m1 = c1, m2 = c1 && c2, m3 = m2 && c3;
        int dp = __shfl(d3, lane - 16, 64);  // prev quad's last dst (q=0: unused)
        int dn = __shfl(d0, lane + 16, 64);  // next quad's first dst (q=3: unused)
        bool contPrev = (q > 0) && (d0 == dp);
        bool flush3 = (q == 3) || (d3 != dn);

#pragma unroll
        for (int tt = 0; tt < 2; ++tt) {
            f32x4 acc = {0.f, 0.f, 0.f, 0.f};
#pragma unroll
            for (int c = 0; c < 12; ++c)
                acc = __builtin_amdgcn_mfma_f32_16x16x32_bf16(a[c], B[tt * 12 + c], acc, 0, 0, 0);
            float v0 = acc[0] + bb[tt], v1 = acc[1] + bb[tt];
            float v2 = acc[2] + bb[tt], v3 = acc[3] + bb[tt];
            v0 *= __builtin_amdgcn_rcpf(1.f + __expf(-v0));  // SiLU
            v1 *= __builtin_amdgcn_rcpf(1.f + __expf(-v1));
            v2 *= __builtin_amdgcn_rcpf(1.f + __expf(-v2));
            v3 *= __builtin_amdgcn_rcpf(1.f + __expf(-v3));
            // quad-local segmented prefix
            float s0 = v0;
            float s1 = v1 + (c1 ? s0 : 0.f);
            float s2 = v2 + (c2 ? s1 : 0.f);
            float s3 = v3 + (c3 ? s2 : 0.f);
            // cross-quad carry: 3 iterations propagate q0->q1->q2->q3
            float carry = 0.f;
#pragma unroll
            for (int it = 0; it < 3; ++it) {
                float ps = __shfl(s3 + (m3 ? carry : 0.f), lane - 16, 64);
                carry = contPrev ? ps : 0.f;
            }
            s0 += carry;
            s1 += m1 ? carry : 0.f;
            s2 += m2 ? carry : 0.f;
            s3 += m3 ? carry : 0.f;
            float* basep = aggF + (t0 + tt) * 16 + n;
            if (!c1) atomicAdd(basep + (size_t)d0 * 128, s0);
            if (!c2) atomicAdd(basep + (size_t)d1 * 128, s1);
            if (!c3) atomicAdd(basep + (size_t)d2 * 128, s2);
            if (flush3) atomicAdd(basep + (size_t)d3 * 128, s3);
        }
    }
}

// ---- fused attention sum + output: one wave per src node, edges sorted by src ----
// out[n] = sum_{e in segS(n)} aggW[dst_e] + degS[n]*bc + bo
__global__ __launch_bounds__(256) void out_gather(const int* __restrict__ offS,
                                                  const int* __restrict__ ss_dst,
                                                  const float* __restrict__ aggW,
                                                  const float* __restrict__ bc,
                                                  const float* __restrict__ bo,
                                                  float* __restrict__ out) {
    int tid = threadIdx.x;
    int wave = tid >> 6;
    int lane = tid & 63;
    int node = blockIdx.x * 4 + wave;
    if (node >= N_NODES) return;
    int e0 = offS[node], e1 = offS[node + 1];
    float a0 = 0.f, a1 = 0.f;  // lane owns cols 2*lane, 2*lane+1
    for (int base = e0; base < e1; base += 16) {
        int m = e1 - base;
        if (m > 16) m = 16;
        int ii = base + (lane & 15);
        if (ii > e1 - 1) ii = e1 - 1;
        int idxv = ss_dst[ii];  // coalesced, 4-way broadcast
#pragma unroll
        for (int i = 0; i < 16; ++i) {
            bool val = i < m;  // wave-uniform
            int d = __shfl(idxv, val ? i : 0, 64);
            f32x2 h = *(const f32x2*)(aggW + (size_t)d * 128 + lane * 2);
            a0 += val ? h[0] : 0.f;
            a1 += val ? h[1] : 0.f;
        }
    }
    float deg = (float)(e1 - e0);
    f32x2 o;
    o[0] = a0 + deg * bc[lane * 2] + bo[lane * 2];
    o[1] = a1 + deg * bc[lane * 2 + 1] + bo[lane * 2 + 1];
    *(f32x2*)(out + (size_t)node * 128 + lane * 2) = o;
}

extern "C" void kernel_launch(void* const* d_in, const int* in_sizes, int n_in,
                              void* d_out, int out_size, void* d_ws, size_t ws_size,
                              hipStream_t stream) {
    const float* x  = (const float*)d_in[0];
    const int* ei   = (const int*)d_in[1];
    const float* ea = (const float*)d_in[2];
    const float* We = (const float*)d_in[3];
    const float* be = (const float*)d_in[4];
    const float* Wg = (const float*)d_in[5];
    const float* bg = (const float*)d_in[6];
    // d_in[7]=Wa, d_in[8]=ba: dead — softmax over a size-1 axis is identically 1
    const float* Wo = (const float*)d_in[9];
    const float* bo = (const float*)d_in[10];
    float* out = (float*)d_out;

    const int* srcIdx = ei;            // edge_index[0]
    const int* dstIdx = ei + N_EDGES;  // edge_index[1]

    char* ws = (char*)d_ws;
    u16*   PBe    = (u16*)(ws + 0);          // 96 KiB  [W3;W2;W1] K=384
    u16*   PBc    = (u16*)(ws + 98304);      // 32 KiB  (Wg@Wo packed)
    float* bc     = (float*)(ws + 131072);   // 512 B   (bg@Wo)
    u16*   Xbf    = (u16*)(ws + 262144);     // [N,128] bf16, 12.8 MB -> ends 13,062,144
    int4*  sdP    = (int4*)(ws + 13062144);  // 12.8 MB (e,src,dst,0) dst-sorted -> ends 25,862,144
    float* aggW   = (float*)(ws + 262144);   // alias over Xbf+sdP (dead after agg), 25.6 MB
    int*   ss_dst = (int*)(ws + 25862144);   // 3.2 MB dst, src-sorted -> ends 29,062,144
    float* aggF   = (float*)(ws + 29062144); // [N,128] f32, 25.6 MB -> ends 54,662,144
    int*   degD   = (int*)(ws + 54662144);   // 200 KB (degS contiguous after)
    int*   degS   = (int*)(ws + 54862144);   // 200 KB
    int*   offD   = (int*)(ws + 55062144);   // 200,016 B
    int*   offS   = (int*)(ws + 55262160);   // 200,016 B
    int*   curD   = (int*)(ws + 55462176);   // 200 KB
    int*   curS   = (int*)(ws + 55662176);   // 200 KB -> ends 55,862,176

    // 1: all preprocessing + zeroing in one kernel
    prep_kernel<<<4856, 256, 0, stream>>>(x, We, Wg, bg, Wo, Xbf, PBe, PBc, bc, aggF, degD);

    // 2-4: counting sorts (by dst for agg, by src for attn)
    hist_kernel<<<3125, 256, 0, stream>>>(srcIdx, dstIdx, degD, degS);
    scan_kernel<<<2, 256, 0, stream>>>(degD, degS, offD, curD, offS, curS);
    scatter_kernel<<<3125, 256, 0, stream>>>(srcIdx, dstIdx, curD, curS, sdP, ss_dst);

    // 5: edge-tile message GEMM (K=384, reg-resident B) + run-collapsed atomic agg
    agg_fused<<<6250, 256, 0, stream>>>(ea, Xbf, PBe, be, sdP, aggF);

    // 6: aggW = agg @ (Wg@Wo)   (writes over dead Xbf/sdP)
    gemm_mfma<<<782, 256, 0, stream>>>(aggF, PBc, aggW, N_NODES);

    // 7: out[n] = sum over src-segment of aggW[dst] + degS*bc + bo
    out_gather<<<12500, 256, 0, stream>>>(offS, ss_dst, aggW, bc, bo, out);

    (void)in_sizes; (void)n_in; (void)out_size; (void)ws_size;
}